// Round 17
// baseline (3489.421 us; speedup 1.0000x reference)
//
#include <hip/hip_runtime.h>
#include <hip/hip_bf16.h>

#define DEV static __device__ __forceinline__

typedef __attribute__((ext_vector_type(8))) short bf16x8;
typedef __attribute__((ext_vector_type(4))) float f32x4;
#define MFMA16 __builtin_amdgcn_mfma_f32_16x16x32_bf16

DEV unsigned short f2bf_rn(float x) {
  unsigned u = __float_as_uint(x);
  u = u + 0x7fffu + ((u >> 16) & 1u);
  return (unsigned short)(u >> 16);
}
DEV unsigned pack2(float a, float b) {
  return (unsigned)f2bf_rn(a) | ((unsigned)f2bf_rn(b) << 16);
}
DEV float lo2f(unsigned w) { return __uint_as_float(w << 16); }
DEV float hi2f(unsigned w) { return __uint_as_float(w & 0xffff0000u); }
DEV float u16f(unsigned short v) { return __uint_as_float(((unsigned)v) << 16); }

constexpr int H_ = 187, MS_ = 20, MOB_ = 10, D_ = 128, NH_ = 4, NL_ = 4,
              CE_ = 16, NAT_ = 5, NCT_ = 256, HEXC_ = 29, B_ = 1024;
constexpr int S_ = H_ + 2;
constexpr int XST = 84;      // xln row stride u32 (84%32=20 -> 2-way b128)
constexpr int QOFF = 64;     // Q staging col (u32) within xln row
constexpr int PST = 36;      // area P/K row stride u32
constexpr int AST = 68;      // area FFN-hidden row stride u32
constexpr int VTS = 100;

constexpr int VT_OFF   = 192 * PST;          // 6912
constexpr int CORR_OFF = VT_OFF + 32 * VTS;  // 10112
constexpr int LSUM_OFF = CORR_OFF + 192;
constexpr int GV_OFF   = LSUM_OFF + 192;
constexpr int PO_OFF   = GV_OFF + 128;
constexpr int H1_OFF   = PO_OFF + 128;
constexpr int H2_OFF   = H1_OFF + 128;       // ends 11008 < 13056

constexpr int OFF_HEX = B_ * NAT_;
constexpr int OFF_TGT = OFF_HEX + B_ * H_;
constexpr int OFF_VAL = OFF_TGT + B_ * MS_;

constexpr float SCALE = 0.17677669529663687f;

constexpr int WS_Q = 0;
constexpr int WS_O = WS_Q + 4 * 384 * 128;
constexpr int WS_F1 = WS_O + 4 * 128 * 128;
constexpr int WS_F2 = WS_F1 + 4 * 512 * 128;
constexpr int WS_TOT = WS_F2 + 4 * 128 * 512;

struct Params {
  const float *scalars, *stacks, *obstacles, *reach;
  const int  *n_stacks;
  const float *cemb, *pos_emb, *tte;
  const float *hexW, *hexB, *hexG, *hexBe;
  const float *heroW, *heroB, *heroG, *heroBe;
  const float *gW, *gB;
  const float *ln1g, *ln1b, *qkvW, *qkvB, *oW, *oB;
  const float *ln2g, *ln2b, *f1W, *f1B, *f2W, *f2B;
  const float *plng, *plnb;
  const float *atW1, *atB1, *atW2, *atB2;
  const float *hxW1, *hxB1, *hxW2, *hxB2;
  const float *tgW1, *tgB1, *tgW2, *tgB2;
  const float *vlW1, *vlB1, *vlW2, *vlB2;
  const unsigned short *wsb;
  float *out;
};

DEV bf16x8 ldAx(const unsigned* buf, int stride, int mbase, int cbase, int lane) {
  return *(const bf16x8*)(buf + (mbase + (lane & 15)) * stride + cbase +
                          ((lane >> 4) << 2));
}
DEV bf16x8 ldBw(const float* q) {
  bf16x8 r;
#pragma unroll
  for (int j = 0; j < 8; ++j) r[j] = (short)f2bf_rn(q[j]);
  return r;
}
template <bool WSB>
DEV bf16x8 ldB(const unsigned short* wb, const float* wf, int off) {
  if constexpr (WSB) return *(const bf16x8*)(wb + off);
  else return ldBw(wf + off);
}

__global__ __launch_bounds__(256) void convw_kernel(const float *qkv,
                                                    const float *o,
                                                    const float *f1,
                                                    const float *f2,
                                                    unsigned short *ws) {
  int i = blockIdx.x * 256 + threadIdx.x;
  if (i < WS_O) ws[i] = f2bf_rn(qkv[i - WS_Q]);
  else if (i < WS_F1) ws[i] = f2bf_rn(o[i - WS_O]);
  else if (i < WS_F2) ws[i] = f2bf_rn(f1[i - WS_F1]);
  else if (i < WS_TOT) ws[i] = f2bf_rn(f2[i - WS_F2]);
}

template <bool WSB>
__global__ __launch_bounds__(768, 1) void battle_kernel(Params p) {
  __shared__ __align__(16) unsigned xln[192 * XST];   // 64512 B
  __shared__ __align__(16) unsigned area[192 * AST];  // 52224 B
  __shared__ int svalid[MS_], sposc[MS_];

  const int b = blockIdx.x;
  const int tid = threadIdx.x;
  const int lane = tid & 63;
  const int wave = tid >> 6;            // 0..11, owns rows 16w..16w+16
  const int colb = lane & 15;           // my column-in-tile
  const int row0 = wave * 16 + ((lane >> 4) << 2);  // my 4 rows start
  const float *sc = p.scalars + b * 19;

  float *areaF = (float *)area;
  unsigned short *xln16 = (unsigned short *)xln;
  unsigned short *P16 = (unsigned short *)area;
  unsigned short *vt16 = (unsigned short *)(area + VT_OFF);
  unsigned short *hid16 = (unsigned short *)area;   // FFN view [192][AST*2]

  float *hexcont = (float *)area;
  int   *cids    = (int *)area + 5440;
  float *obsch   = (float *)area + 5632;

  if (tid < D_) {
    float g0 = sc[1] * 0.02f, g1 = sc[4] * 0.1f, g2 = sc[5] * 0.1f;
    float g3 = sc[6], g4 = sc[3];
    const float *w = p.gW + tid * 5;
    areaF[GV_OFF + tid] = p.gB[tid] + g0 * w[0] + g1 * w[1] + g2 * w[2] +
                          g3 * w[3] + g4 * w[4];
  }
  for (int i = tid; i < H_ * HEXC_; i += 768) hexcont[i] = 0.f;
  for (int i = tid; i < H_; i += 768) { cids[i] = 0; obsch[i] = 0.f; }
  if (tid >= 189 && tid < 192) {
    for (int c = 0; c < 64; ++c) xln[tid * XST + c] = 0u;
  }
  __syncthreads();

  if (tid < MS_) {
    const float *st = p.stacks + (b * MS_ + tid) * 35;
    int pos = (int)st[18];
    float alive = st[23];
    int ns = p.n_stacks[b];
    bool valid = (pos >= 0) && (pos < H_) && (alive >= 0.5f) && (tid < ns);
    svalid[tid] = valid ? 1 : 0;
    sposc[tid] = min(max(pos, 0), H_ - 1);
    if (valid) {
      float maxhp = fmaxf(st[4], 1.0f);
      float *hc = hexcont + pos * HEXC_;
      hc[0] = 1.0f;
      hc[1] = st[2] * 1e-3f;
      hc[2] = st[3] / maxhp;
      hc[3] = st[8] * 0.01f;  hc[4] = st[9] * 0.01f;
      hc[5] = st[10] * 0.01f; hc[6] = st[11] * 0.01f;
      hc[7] = st[12] * 0.01f; hc[8] = st[13] * 0.01f;
      hc[9] = st[14] * 0.01f; hc[10] = st[15] * 0.01f;
      hc[11] = st[16] * 0.05f; hc[12] = st[17] * 0.05f;
      float s20 = st[20];
      hc[13] = s20;
      hc[14] = (s20 == sc[3]) ? 1.f : 0.f;
      hc[15] = alive;
      hc[16] = st[24]; hc[17] = st[25]; hc[18] = st[26];
      hc[19] = st[27]; hc[20] = st[28]; hc[21] = st[29];
      hc[22] = st[30];
      hc[23] = st[31] * (1.f / 30.f);
      hc[24] = st[33] * 0.2f;
      hc[25] = st[34] * 0.1f;
      hc[26] = (st[0] == sc[2]) ? 1.f : 0.f;
      hc[27] = 0.f; hc[28] = 0.f;
      cids[pos] = min((int)st[1], NCT_ - 1);
    }
  }
  if (tid >= 64 && tid < 64 + MOB_) {
    const float *ob = p.obstacles + (b * MOB_ + (tid - 64)) * 3;
    int opos = (int)ob[2];
    if (ob[0] > 0.f && opos >= 0 && opos < H_) obsch[opos] = 1.0f;
  }
  __syncthreads();

  // ---- tokens -> xln staging (thread-per-row, bf16 pairs) ----
  if (tid < H_) {
    const int r = tid;
    float f[HEXC_ + CE_];
#pragma unroll
    for (int c = 0; c < HEXC_; ++c) f[c] = hexcont[r * HEXC_ + c];
    f[27] = p.reach[b * H_ + r];
    f[28] = obsch[r];
    int cid = cids[r];
#pragma unroll
    for (int e = 0; e < CE_; ++e) f[HEXC_ + e] = p.cemb[cid * CE_ + e];
    float sum = 0.f;
    for (int d2 = 0; d2 < 64; ++d2) {
      const float *w0 = p.hexW + (2 * d2) * 45;
      const float *w1 = w0 + 45;
      float a0 = p.hexB[2 * d2], a1 = 0.f, a2 = 0.f, a3 = 0.f;
      float b0 = p.hexB[2 * d2 + 1], b1 = 0.f, b2 = 0.f, b3 = 0.f;
#pragma unroll
      for (int k = 0; k < 44; k += 4) {
        a0 = fmaf(f[k], w0[k], a0);       a1 = fmaf(f[k + 1], w0[k + 1], a1);
        a2 = fmaf(f[k + 2], w0[k + 2], a2); a3 = fmaf(f[k + 3], w0[k + 3], a3);
        b0 = fmaf(f[k], w1[k], b0);       b1 = fmaf(f[k + 1], w1[k + 1], b1);
        b2 = fmaf(f[k + 2], w1[k + 2], b2); b3 = fmaf(f[k + 3], w1[k + 3], b3);
      }
      a0 = fmaf(f[44], w0[44], a0);
      b0 = fmaf(f[44], w1[44], b0);
      float va = (a0 + a1) + (a2 + a3), vb = (b0 + b1) + (b2 + b3);
      xln[r * XST + d2] = pack2(va, vb);
      sum += va + vb;
    }
    float m = sum * (1.f / 128.f);
    float var = 0.f;
#pragma unroll 4
    for (int d2 = 0; d2 < 64; ++d2) {
      unsigned w = xln[r * XST + d2];
      float t0 = lo2f(w) - m, t1 = hi2f(w) - m;
      var = fmaf(t0, t0, var); var = fmaf(t1, t1, var);
    }
    float rs = rsqrtf(var * (1.f / 128.f) + 1e-5f);
#pragma unroll 2
    for (int d2 = 0; d2 < 64; ++d2) {
      unsigned w = xln[r * XST + d2];
      int d = 2 * d2;
      float v0 = (lo2f(w) - m) * rs * p.hexG[d] + p.hexBe[d] +
                 p.pos_emb[r * D_ + d] + p.tte[d] + areaF[GV_OFF + d];
      float v1 = (hi2f(w) - m) * rs * p.hexG[d + 1] + p.hexBe[d + 1] +
                 p.pos_emb[r * D_ + d + 1] + p.tte[d + 1] + areaF[GV_OFF + d + 1];
      xln[r * XST + d2] = pack2(v0, v1);
    }
  } else if (tid < S_) {
    const int which = tid - H_;
    float f0, f1, f2, f3, f4;
    if (which == 0) {
      f0 = sc[8];  f1 = sc[11] * (1.f / 300.f);
      f2 = sc[10] * 0.1f; f3 = sc[12] * 0.1f; f4 = 0.f;
    } else {
      f0 = sc[14]; f1 = sc[17] * (1.f / 300.f);
      f2 = sc[16] * 0.1f; f3 = sc[18] * 0.1f; f4 = 1.f;
    }
    const int r = tid;
    float sum = 0.f;
    for (int d2 = 0; d2 < 64; ++d2) {
      const float *w0 = p.heroW + (2 * d2) * 5;
      const float *w1 = w0 + 5;
      float va = p.heroB[2 * d2] + f0 * w0[0] + f1 * w0[1] + f2 * w0[2] + f3 * w0[3] + f4 * w0[4];
      float vb = p.heroB[2 * d2 + 1] + f0 * w1[0] + f1 * w1[1] + f2 * w1[2] + f3 * w1[3] + f4 * w1[4];
      xln[r * XST + d2] = pack2(va, vb);
      sum += va + vb;
    }
    float m = sum * (1.f / 128.f);
    float var = 0.f;
    for (int d2 = 0; d2 < 64; ++d2) {
      unsigned w = xln[r * XST + d2];
      float t0 = lo2f(w) - m, t1 = hi2f(w) - m;
      var = fmaf(t0, t0, var); var = fmaf(t1, t1, var);
    }
    float rs = rsqrtf(var * (1.f / 128.f) + 1e-5f);
    for (int d2 = 0; d2 < 64; ++d2) {
      unsigned w = xln[r * XST + d2];
      int d = 2 * d2;
      float v0 = (lo2f(w) - m) * rs * p.heroG[d] + p.heroBe[d] +
                 p.tte[(1 + which) * D_ + d] + areaF[GV_OFF + d];
      float v1 = (hi2f(w) - m) * rs * p.heroG[d + 1] + p.heroBe[d + 1] +
                 p.tte[(1 + which) * D_ + d + 1] + areaF[GV_OFF + d + 1];
      xln[r * XST + d2] = pack2(v0, v1);
    }
  }
  __syncthreads();

  // ---- residual -> registers, C-layout: X[g][nt] = X[row0+g][nt*16+colb] ----
  float X[4][8];
#pragma unroll
  for (int g = 0; g < 4; ++g)
#pragma unroll
    for (int nt = 0; nt < 8; ++nt)
      X[g][nt] = u16f(xln16[(row0 + g) * (XST * 2) + nt * 16 + colb]);

  for (int l = 0; l < NL_; ++l) {
    const float *ln1g = p.ln1g + l * D_, *ln1b = p.ln1b + l * D_;
    const float *qkvW = p.qkvW + l * 3 * D_ * D_, *qkvB = p.qkvB + l * 3 * D_;
    const float *oW = p.oW + l * D_ * D_, *oB = p.oB + l * D_;
    const float *ln2g = p.ln2g + l * D_, *ln2b = p.ln2b + l * D_;
    const float *f1W = p.f1W + l * 4 * D_ * D_, *f1B = p.f1B + l * 4 * D_;
    const float *f2W = p.f2W + l * 4 * D_ * D_, *f2B = p.f2B + l * D_;
    const unsigned short *qkvWb = p.wsb + WS_Q + l * 384 * 128;
    const unsigned short *oWb = p.wsb + WS_O + l * 128 * 128;
    const unsigned short *f1Wb = p.wsb + WS_F1 + l * 512 * 128;
    const unsigned short *f2Wb = p.wsb + WS_F2 + l * 128 * 512;

    __syncthreads();   // area reuse fence (prev FFN hidden / embed scratch)

    // ---- LN1 from registers -> xln (wave-local) ----
    {
      float ga[8], be[8];
#pragma unroll
      for (int nt = 0; nt < 8; ++nt) {
        ga[nt] = ln1g[nt * 16 + colb];
        be[nt] = ln1b[nt * 16 + colb];
      }
#pragma unroll
      for (int g = 0; g < 4; ++g) {
        float s = 0.f;
#pragma unroll
        for (int nt = 0; nt < 8; ++nt) s += X[g][nt];
        s += __shfl_xor(s, 1); s += __shfl_xor(s, 2);
        s += __shfl_xor(s, 4); s += __shfl_xor(s, 8);
        float m = s * (1.f / 128.f);
        float v = 0.f;
#pragma unroll
        for (int nt = 0; nt < 8; ++nt) {
          float t = X[g][nt] - m;
          v = fmaf(t, t, v);
        }
        v += __shfl_xor(v, 1); v += __shfl_xor(v, 2);
        v += __shfl_xor(v, 4); v += __shfl_xor(v, 8);
        float rs = rsqrtf(v * (1.f / 128.f) + 1e-5f);
#pragma unroll
        for (int nt = 0; nt < 8; ++nt)
          xln16[(row0 + g) * (XST * 2) + nt * 16 + colb] =
              f2bf_rn((X[g][nt] - m) * rs * ga[nt] + be[nt]);
      }
    }

    f32x4 oacc[4][2];
#pragma unroll
    for (int h = 0; h < NH_; ++h)
#pragma unroll
      for (int nd = 0; nd < 2; ++nd) oacc[h][nd] = {0.f, 0.f, 0.f, 0.f};

#pragma unroll 1
    for (int h = 0; h < NH_; ++h) {
      // QKV for own rows, all 6 n-tiles (Q0 Q1 K0 K1 V0 V1)
      {
        bf16x8 a0 = ldAx(xln, XST, wave * 16, 0, lane);
        bf16x8 a1 = ldAx(xln, XST, wave * 16, 16, lane);
        bf16x8 a2 = ldAx(xln, XST, wave * 16, 32, lane);
        bf16x8 a3 = ldAx(xln, XST, wave * 16, 48, lane);
        int koff = (lane >> 4) << 3;
#pragma unroll
        for (int ng = 0; ng < 6; ++ng) {
          int nrow0 = (ng < 2) ? (h * 32 + ng * 16)
                    : (ng < 4) ? (128 + h * 32 + (ng - 2) * 16)
                               : (256 + h * 32 + (ng - 4) * 16);
          int roff = (nrow0 + colb) * 128;
          bf16x8 b0 = ldB<WSB>(qkvWb, qkvW, roff + koff);
          bf16x8 b1 = ldB<WSB>(qkvWb, qkvW, roff + 32 + koff);
          bf16x8 b2 = ldB<WSB>(qkvWb, qkvW, roff + 64 + koff);
          bf16x8 b3 = ldB<WSB>(qkvWb, qkvW, roff + 96 + koff);
          float bv = qkvB[nrow0 + colb];
          f32x4 acc = {bv, bv, bv, bv};
          acc = MFMA16(a0, b0, acc, 0, 0, 0);
          acc = MFMA16(a1, b1, acc, 0, 0, 0);
          acc = MFMA16(a2, b2, acc, 0, 0, 0);
          acc = MFMA16(a3, b3, acc, 0, 0, 0);
          if (ng < 2) {        // Q -> own xln Q region (wave-local)
            int col16 = ng * 16 + colb;
#pragma unroll
            for (int g = 0; g < 4; ++g)
              xln16[(row0 + g) * (XST * 2) + QOFF * 2 + col16] = f2bf_rn(acc[g]);
          } else if (ng < 4) { // K -> area P region
            int col16 = (ng - 2) * 16 + colb;
#pragma unroll
            for (int g = 0; g < 4; ++g)
              P16[(row0 + g) * (PST * 2) + col16] = f2bf_rn(acc[g]);
          } else {             // V -> VT (transposed)
            int vcol = (ng - 4) * 16 + colb;
#pragma unroll
            for (int g = 0; g < 4; ++g)
              vt16[vcol * (VTS * 2) + row0 + g] = f2bf_rn(acc[g]);
          }
        }
      }
      __syncthreads();   // K/V visible to all

      bf16x8 qf = ldAx(xln, XST, wave * 16, QOFF, lane);
      bf16x8 kf[12];
#pragma unroll
      for (int nt = 0; nt < 12; ++nt)
        kf[nt] = ldAx(area, PST, nt * 16, 0, lane);
      float mrun = -1e30f, lrun = 0.f;
      const int srow = wave * 16 + colb;
      const int ssub = lane >> 4;
      __syncthreads();   // kf loaded before scores overwrite K

#pragma unroll
      for (int t = 0; t < 3; ++t) {
        {
#pragma unroll
          for (int ntl = 0; ntl < 4; ++ntl) {
            f32x4 s = {0.f, 0.f, 0.f, 0.f};
            s = MFMA16(qf, kf[t * 4 + ntl], s, 0, 0, 0);
            int col16 = ntl * 16 + colb;
#pragma unroll
            for (int g = 0; g < 4; ++g)
              P16[(row0 + g) * (PST * 2) + col16] = f2bf_rn(s[g]);
          }
        }
        {
          float tm = -1e30f;
          int cb = ssub * 8;
#pragma unroll
          for (int i = 0; i < 8; ++i) {
            int c2 = cb + i;
            unsigned w = area[srow * PST + c2];
            float v0 = lo2f(w) * SCALE, v1 = hi2f(w) * SCALE;
            if (t == 2 && c2 == 30) v1 = -1e30f;
            if (t == 2 && c2 == 31) { v0 = -1e30f; v1 = -1e30f; }
            tm = fmaxf(tm, fmaxf(v0, v1));
          }
          tm = fmaxf(tm, __shfl_xor(tm, 16));
          tm = fmaxf(tm, __shfl_xor(tm, 32));
          float mnew = fmaxf(mrun, tm);
          float corrv = __expf(mrun - mnew);
          float ts = 0.f;
#pragma unroll
          for (int i = 0; i < 8; ++i) {
            int c2 = cb + i;
            unsigned w = area[srow * PST + c2];
            float e0 = __expf(lo2f(w) * SCALE - mnew);
            float e1 = __expf(hi2f(w) * SCALE - mnew);
            if (t == 2 && c2 == 30) e1 = 0.f;
            if (t == 2 && c2 == 31) { e0 = 0.f; e1 = 0.f; }
            ts += e0 + e1;
            area[srow * PST + c2] = pack2(e0, e1);
          }
          ts += __shfl_xor(ts, 16);
          ts += __shfl_xor(ts, 32);
          lrun = lrun * corrv + ts;
          mrun = mnew;
          if (ssub == 0) {
            areaF[CORR_OFF + srow] = corrv;
            if (t == 2) areaF[LSUM_OFF + srow] = lrun;
          }
        }
        {
          float c0 = areaF[CORR_OFF + row0], c1 = areaF[CORR_OFF + row0 + 1];
          float c2v = areaF[CORR_OFF + row0 + 2], c3 = areaF[CORR_OFF + row0 + 3];
#pragma unroll
          for (int nd = 0; nd < 2; ++nd) {
            f32x4 a = oacc[h][nd];
            a[0] *= c0; a[1] *= c1; a[2] *= c2v; a[3] *= c3;
#pragma unroll
            for (int kt = 0; kt < 2; ++kt) {
              bf16x8 af = ldAx(area, PST, wave * 16, kt * 16, lane);
              bf16x8 bv = *(const bf16x8*)(area + VT_OFF +
                            (nd * 16 + colb) * VTS + t * 32 + kt * 16 +
                            ((lane >> 4) << 2));
              a = MFMA16(af, bv, a, 0, 0, 0);
            }
            oacc[h][nd] = a;
          }
          if (t == 2) {
            float i0 = 1.f / areaF[LSUM_OFF + row0];
            float i1 = 1.f / areaF[LSUM_OFF + row0 + 1];
            float i2 = 1.f / areaF[LSUM_OFF + row0 + 2];
            float i3 = 1.f / areaF[LSUM_OFF + row0 + 3];
#pragma unroll
            for (int nd = 0; nd < 2; ++nd) {
              f32x4 a = oacc[h][nd];
              a[0] *= i0; a[1] *= i1; a[2] *= i2; a[3] *= i3;
              oacc[h][nd] = a;
            }
          }
        }
      }
      __syncthreads();   // before next head overwrites K/V/P
    }  // heads

    // ---- attn-out -> own xln rows (wave-local, C-layout) ----
#pragma unroll
    for (int h = 0; h < NH_; ++h)
#pragma unroll
      for (int nd = 0; nd < 2; ++nd) {
        int col16 = h * 32 + nd * 16 + colb;
        f32x4 a = oacc[h][nd];
#pragma unroll
        for (int g = 0; g < 4; ++g)
          xln16[(row0 + g) * (XST * 2) + col16] = f2bf_rn(a[g]);
      }

    // ---- O-projection (own rows x all cols), residual into X ----
    {
      bf16x8 a0 = ldAx(xln, XST, wave * 16, 0, lane);
      bf16x8 a1 = ldAx(xln, XST, wave * 16, 16, lane);
      bf16x8 a2 = ldAx(xln, XST, wave * 16, 32, lane);
      bf16x8 a3 = ldAx(xln, XST, wave * 16, 48, lane);
      int koff = (lane >> 4) << 3;
#pragma unroll
      for (int nt = 0; nt < 8; ++nt) {
        int roff = (nt * 16 + colb) * 128;
        bf16x8 b0 = ldB<WSB>(oWb, oW, roff + koff);
        bf16x8 b1 = ldB<WSB>(oWb, oW, roff + 32 + koff);
        bf16x8 b2 = ldB<WSB>(oWb, oW, roff + 64 + koff);
        bf16x8 b3 = ldB<WSB>(oWb, oW, roff + 96 + koff);
        float bv = oB[nt * 16 + colb];
        f32x4 acc = {bv, bv, bv, bv};
        acc = MFMA16(a0, b0, acc, 0, 0, 0);
        acc = MFMA16(a1, b1, acc, 0, 0, 0);
        acc = MFMA16(a2, b2, acc, 0, 0, 0);
        acc = MFMA16(a3, b3, acc, 0, 0, 0);
#pragma unroll
        for (int g = 0; g < 4; ++g) X[g][nt] += acc[g];
      }
    }

    // ---- LN2 from registers -> xln (wave-local) ----
    {
      float ga[8], be[8];
#pragma unroll
      for (int nt = 0; nt < 8; ++nt) {
        ga[nt] = ln2g[nt * 16 + colb];
        be[nt] = ln2b[nt * 16 + colb];
      }
#pragma unroll
      for (int g = 0; g < 4; ++g) {
        float s = 0.f;
#pragma unroll
        for (int nt = 0; nt < 8; ++nt) s += X[g][nt];
        s += __shfl_xor(s, 1); s += __shfl_xor(s, 2);
        s += __shfl_xor(s, 4); s += __shfl_xor(s, 8);
        float m = s * (1.f / 128.f);
        float v = 0.f;
#pragma unroll
        for (int nt = 0; nt < 8; ++nt) {
          float t = X[g][nt] - m;
          v = fmaf(t, t, v);
        }
        v += __shfl_xor(v, 1); v += __shfl_xor(v, 2);
        v += __shfl_xor(v, 4); v += __shfl_xor(v, 8);
        float rs = rsqrtf(v * (1.f / 128.f) + 1e-5f);
#pragma unroll
        for (int nt = 0; nt < 8; ++nt)
          xln16[(row0 + g) * (XST * 2) + nt * 16 + colb] =
              f2bf_rn((X[g][nt] - m) * rs * ga[nt] + be[nt]);
      }
    }
    __syncthreads();   // retire P/VT reads before FFN hidden overwrites area

    // ---- FFN (wave-local; hidden bounced through area own rows) ----
    {
      bf16x8 a0 = ldAx(xln, XST, wave * 16, 0, lane);
      bf16x8 a1 = ldAx(xln, XST, wave * 16, 16, lane);
      bf16x8 a2 = ldAx(xln, XST, wave * 16, 32, lane);
      bf16x8 a3 = ldAx(xln, XST, wave * 16, 48, lane);
      int koff = (lane >> 4) << 3;
      f32x4 acc2[8];
#pragma unroll
      for (int nt = 0; nt < 8; ++nt) {
        float bv = f2B[nt * 16 + colb];
        acc2[nt] = {bv, bv, bv, bv};
      }
#pragma unroll 1
      for (int chunk = 0; chunk < 4; ++chunk) {
#pragma unroll
        for (int nt = 0; nt < 8; ++nt) {
          int roff = (chunk * 128 + nt * 16 + colb) * 128;
          bf16x8 b0 = ldB<WSB>(f1Wb, f1W, roff + koff);
          bf16x8 b1 = ldB<WSB>(f1Wb, f1W, roff + 32 + koff);
          bf16x8 b2 = ldB<WSB>(f1Wb, f1W, roff + 64 + koff);
          bf16x8 b3 = ldB<WSB>(f1Wb, f1W, roff + 96 + koff);
          float bv = f1B[chunk * 128 + nt * 16 + colb];
          f32x4 acc = {bv, bv, bv, bv};
          acc = MFMA16(a0, b0, acc, 0, 0, 0);
          acc = MFMA16(a1, b1, acc, 0, 0, 0);
          acc = MFMA16(a2, b2, acc, 0, 0, 0);
          acc = MFMA16(a3, b3, acc, 0, 0, 0);
          int col16 = nt * 16 + colb;
#pragma unroll
          for (int g = 0; g < 4; ++g)
            hid16[(row0 + g) * (AST * 2) + col16] = f2bf_rn(fmaxf(acc[g], 0.f));
        }
        // FFN2 partial (A = own hidden rows; wave-local ordering)
        bf16x8 h0 = ldAx(area, AST, wave * 16, 0, lane);
        bf16x8 h1 = ldAx(area, AST, wave * 16, 16, lane);
        bf16x8 h2 = ldAx(area, AST, wave * 16, 32, lane);
        bf16x8 h3 = ldAx(area, AST, wave * 16, 48, lane);
#pragma unroll
        for (int nt = 0; nt < 8; ++nt) {
          int roff = (nt * 16 + colb) * 512 + chunk * 128;
          bf16x8 b0 = ldB<WSB>(f2Wb, f2W, roff + koff);
          bf16x8 b1 = ldB<WSB>(f2Wb, f2W, roff + 32 + koff);
          bf16x8 b2 = ldB<WSB>(f2Wb, f2W, roff + 64 + koff);
          bf16x8 b3 = ldB<WSB>(f2Wb, f2W, roff + 96 + koff);
          f32x4 a = acc2[nt];
          a = MFMA16(h0, b0, a, 0, 0, 0);
          a = MFMA16(h1, b1, a, 0, 0, 0);
          a = MFMA16(h2, b2, a, 0, 0, 0);
          a = MFMA16(h3, b3, a, 0, 0, 0);
          acc2[nt] = a;
        }
      }
#pragma unroll
      for (int nt = 0; nt < 8; ++nt)
#pragma unroll
        for (int g = 0; g < 4; ++g) X[g][nt] += acc2[nt][g];
    }
  }  // layers

  // ---- post-LN from registers -> xln ----
  {
    float ga[8], be[8];
#pragma unroll
    for (int nt = 0; nt < 8; ++nt) {
      ga[nt] = p.plng[nt * 16 + colb];
      be[nt] = p.plnb[nt * 16 + colb];
    }
#pragma unroll
    for (int g = 0; g < 4; ++g) {
      float s = 0.f;
#pragma unroll
      for (int nt = 0; nt < 8; ++nt) s += X[g][nt];
      s += __shfl_xor(s, 1); s += __shfl_xor(s, 2);
      s += __shfl_xor(s, 4); s += __shfl_xor(s, 8);
      float m = s * (1.f / 128.f);
      float v = 0.f;
#pragma unroll
      for (int nt = 0; nt < 8; ++nt) {
        float t = X[g][nt] - m;
        v = fmaf(t, t, v);
      }
      v += __shfl_xor(v, 1); v += __shfl_xor(v, 2);
      v += __shfl_xor(v, 4); v += __shfl_xor(v, 8);
      float rs = rsqrtf(v * (1.f / 128.f) + 1e-5f);
#pragma unroll
      for (int nt = 0; nt < 8; ++nt)
        xln16[(row0 + g) * (XST * 2) + nt * 16 + colb] =
            f2bf_rn((X[g][nt] - m) * rs * ga[nt] + be[nt]);
    }
  }
  __syncthreads();

  // ---- pooled mean ----
  if (tid < D_) {
    const int d2 = tid >> 1;
    const bool hi = tid & 1;
    float s0 = 0.f, s1 = 0.f;
    int r = 0;
    for (; r + 2 <= S_; r += 2) {
      unsigned w0 = xln[r * XST + d2], w1 = xln[(r + 1) * XST + d2];
      s0 += hi ? hi2f(w0) : lo2f(w0);
      s1 += hi ? hi2f(w1) : lo2f(w1);
    }
    unsigned wl = xln[(S_ - 1) * XST + d2];
    s0 += hi ? hi2f(wl) : lo2f(wl);
    areaF[PO_OFF + tid] = (s0 + s1) * (1.f / (float)S_);
  }
  __syncthreads();
  if (tid < D_) {
    const float *wa = p.atW1 + tid * D_;
    const float *wv = p.vlW1 + tid * D_;
    float a0 = p.atB1[tid], a1 = 0.f, vv0 = p.vlB1[tid], vv1 = 0.f;
#pragma unroll 4
    for (int k = 0; k < D_; k += 2) {
      float pk0 = areaF[PO_OFF + k], pk1 = areaF[PO_OFF + k + 1];
      a0 = fmaf(pk0, wa[k], a0);   a1 = fmaf(pk1, wa[k + 1], a1);
      vv0 = fmaf(pk0, wv[k], vv0); vv1 = fmaf(pk1, wv[k + 1], vv1);
    }
    areaF[H1_OFF + tid] = fmaxf(a0 + a1, 0.f);
    areaF[H2_OFF + tid] = fmaxf(vv0 + vv1, 0.f);
  }
  __syncthreads();

  if (tid < H_) {
    float hh[64];
#pragma unroll
    for (int j = 0; j < 64; ++j) hh[j] = p.hxB1[j];
    for (int kb = 0; kb < 8; ++kb) {
      float xr[16];
#pragma unroll
      for (int i2 = 0; i2 < 8; ++i2) {
        unsigned w = xln[tid * XST + kb * 8 + i2];
        xr[2 * i2] = lo2f(w); xr[2 * i2 + 1] = hi2f(w);
      }
      const float *w = p.hxW1 + kb * 16;
#pragma unroll
      for (int j = 0; j < 64; ++j) {
#pragma unroll
        for (int i = 0; i < 16; ++i)
          hh[j] = fmaf(xr[i], w[j * D_ + i], hh[j]);
      }
    }
    float o = p.hxB2[0];
#pragma unroll
    for (int j = 0; j < 64; ++j) o = fmaf(fmaxf(hh[j], 0.f), p.hxW2[j], o);
    p.out[OFF_HEX + b * H_ + tid] = o;
  }
  if (tid < NAT_) {
    const float *w = p.atW2 + tid * D_;
    float o0 = p.atB2[tid], o1 = 0.f, o2 = 0.f, o3 = 0.f;
#pragma unroll 4
    for (int k = 0; k < D_; k += 4) {
      o0 = fmaf(areaF[H1_OFF + k], w[k], o0);
      o1 = fmaf(areaF[H1_OFF + k + 1], w[k + 1], o1);
      o2 = fmaf(areaF[H1_OFF + k + 2], w[k + 2], o2);
      o3 = fmaf(areaF[H1_OFF + k + 3], w[k + 3], o3);
    }
    p.out[b * NAT_ + tid] = (o0 + o1) + (o2 + o3);
  }
  if (tid == 190) {
    float o0 = p.vlB2[0], o1 = 0.f, o2 = 0.f, o3 = 0.f;
#pragma unroll 4
    for (int k = 0; k < D_; k += 4) {
      o0 = fmaf(areaF[H2_OFF + k], p.vlW2[k], o0);
      o1 = fmaf(areaF[H2_OFF + k + 1], p.vlW2[k + 1], o1);
      o2 = fmaf(areaF[H2_OFF + k + 2], p.vlW2[k + 2], o2);
      o3 = fmaf(areaF[H2_OFF + k + 3], p.vlW2[k + 3], o3);
    }
    p.out[OFF_VAL + b] = (o0 + o1) + (o2 + o3);
  }
  if (tid >= 32 && tid < 32 + MS_) {
    int si = tid - 32;
    float o;
    if (svalid[si]) {
      int r = sposc[si];
      float hh[64];
#pragma unroll
      for (int j = 0; j < 64; ++j) hh[j] = p.tgB1[j];
      for (int kb = 0; kb < 8; ++kb) {
        float xr[16];
#pragma unroll
        for (int i2 = 0; i2 < 8; ++i2) {
          unsigned w = xln[r * XST + kb * 8 + i2];
          xr[2 * i2] = lo2f(w); xr[2 * i2 + 1] = hi2f(w);
        }
        const float *w = p.tgW1 + kb * 16;
#pragma unroll
        for (int j = 0; j < 64; ++j) {
#pragma unroll
          for (int i = 0; i < 16; ++i)
            hh[j] = fmaf(xr[i], w[j * D_ + i], hh[j]);
        }
      }
      o = p.tgB2[0];
#pragma unroll
      for (int j = 0; j < 64; ++j) o = fmaf(fmaxf(hh[j], 0.f), p.tgW2[j], o);
    } else {
      o = -1e9f;
    }
    p.out[OFF_TGT + b * MS_ + si] = o;
  }
}

extern "C" void kernel_launch(void* const* d_in, const int* in_sizes, int n_in,
                              void* d_out, int out_size, void* d_ws, size_t ws_size,
                              hipStream_t stream) {
  (void)in_sizes; (void)n_in; (void)out_size;
  Params p;
  p.scalars = (const float *)d_in[0];
  p.stacks = (const float *)d_in[1];
  p.obstacles = (const float *)d_in[2];
  p.reach = (const float *)d_in[3];
  p.n_stacks = (const int *)d_in[4];
  p.cemb = (const float *)d_in[5];
  p.pos_emb = (const float *)d_in[6];
  p.tte = (const float *)d_in[7];
  p.hexW = (const float *)d_in[8];  p.hexB = (const float *)d_in[9];
  p.hexG = (const float *)d_in[10]; p.hexBe = (const float *)d_in[11];
  p.heroW = (const float *)d_in[12]; p.heroB = (const float *)d_in[13];
  p.heroG = (const float *)d_in[14]; p.heroBe = (const float *)d_in[15];
  p.gW = (const float *)d_in[16]; p.gB = (const float *)d_in[17];
  p.ln1g = (const float *)d_in[18]; p.ln1b = (const float *)d_in[19];
  p.qkvW = (const float *)d_in[20]; p.qkvB = (const float *)d_in[21];
  p.oW = (const float *)d_in[22]; p.oB = (const float *)d_in[23];
  p.ln2g = (const float *)d_in[24]; p.ln2b = (const float *)d_in[25];
  p.f1W = (const float *)d_in[26]; p.f1B = (const float *)d_in[27];
  p.f2W = (const float *)d_in[28]; p.f2B = (const float *)d_in[29];
  p.plng = (const float *)d_in[30]; p.plnb = (const float *)d_in[31];
  p.atW1 = (const float *)d_in[32]; p.atB1 = (const float *)d_in[33];
  p.atW2 = (const float *)d_in[34]; p.atB2 = (const float *)d_in[35];
  p.hxW1 = (const float *)d_in[36]; p.hxB1 = (const float *)d_in[37];
  p.hxW2 = (const float *)d_in[38]; p.hxB2 = (const float *)d_in[39];
  p.tgW1 = (const float *)d_in[40]; p.tgB1 = (const float *)d_in[41];
  p.tgW2 = (const float *)d_in[42]; p.tgB2 = (const float *)d_in[43];
  p.vlW1 = (const float *)d_in[44]; p.vlB1 = (const float *)d_in[45];
  p.vlW2 = (const float *)d_in[46]; p.vlB2 = (const float *)d_in[47];
  p.out = (float *)d_out;
  bool usews = ws_size >= (size_t)WS_TOT * 2;
  if (usews) {
    p.wsb = (const unsigned short *)d_ws;
    convw_kernel<<<dim3((WS_TOT + 255) / 256), dim3(256), 0, stream>>>(
        p.qkvW, p.oW, p.f1W, p.f2W, (unsigned short *)d_ws);
    battle_kernel<true><<<dim3(B_), dim3(768), 0, stream>>>(p);
  } else {
    p.wsb = nullptr;
    battle_kernel<false><<<dim3(B_), dim3(768), 0, stream>>>(p);
  }
}

// Round 18
// 2084.603 us; speedup vs baseline: 1.6739x; 1.6739x over previous
//
#include <hip/hip_runtime.h>
#include <hip/hip_bf16.h>

#define DEV static __device__ __forceinline__

typedef __attribute__((ext_vector_type(8))) short bf16x8;
typedef __attribute__((ext_vector_type(4))) float f32x4;
#define MFMA16 __builtin_amdgcn_mfma_f32_16x16x32_bf16

DEV unsigned short f2bf_rn(float x) {
  unsigned u = __float_as_uint(x);
  u = u + 0x7fffu + ((u >> 16) & 1u);
  return (unsigned short)(u >> 16);
}
DEV unsigned pack2(float a, float b) {
  return (unsigned)f2bf_rn(a) | ((unsigned)f2bf_rn(b) << 16);
}
DEV float lo2f(unsigned w) { return __uint_as_float(w << 16); }
DEV float hi2f(unsigned w) { return __uint_as_float(w & 0xffff0000u); }

constexpr int H_ = 187, MS_ = 20, MOB_ = 10, D_ = 128, NH_ = 4, NL_ = 4,
              CE_ = 16, NAT_ = 5, NCT_ = 256, HEXC_ = 29, B_ = 1024;
constexpr int S_ = H_ + 2;
constexpr int ST = 68;
constexpr int PST = 36;
constexpr int VTS = 100;

constexpr int VT_OFF   = 192 * PST;
constexpr int CORR_OFF = VT_OFF + 32 * VTS;
constexpr int LSUM_OFF = CORR_OFF + 192;
constexpr int GV_OFF   = LSUM_OFF + 192;
constexpr int PO_OFF   = GV_OFF + 128;
constexpr int H1_OFF   = PO_OFF + 128;
constexpr int H2_OFF   = H1_OFF + 128;

constexpr int OFF_HEX = B_ * NAT_;
constexpr int OFF_TGT = OFF_HEX + B_ * H_;
constexpr int OFF_VAL = OFF_TGT + B_ * MS_;

constexpr float SCALE = 0.17677669529663687f;

constexpr int WS_Q = 0;
constexpr int WS_O = WS_Q + 4 * 384 * 128;
constexpr int WS_F1 = WS_O + 4 * 128 * 128;
constexpr int WS_F2 = WS_F1 + 4 * 512 * 128;
constexpr int WS_TOT = WS_F2 + 4 * 128 * 512;

struct Params {
  const float *scalars, *stacks, *obstacles, *reach;
  const int  *n_stacks;
  const float *cemb, *pos_emb, *tte;
  const float *hexW, *hexB, *hexG, *hexBe;
  const float *heroW, *heroB, *heroG, *heroBe;
  const float *gW, *gB;
  const float *ln1g, *ln1b, *qkvW, *qkvB, *oW, *oB;
  const float *ln2g, *ln2b, *f1W, *f1B, *f2W, *f2B;
  const float *plng, *plnb;
  const float *atW1, *atB1, *atW2, *atB2;
  const float *hxW1, *hxB1, *hxW2, *hxB2;
  const float *tgW1, *tgB1, *tgW2, *tgB2;
  const float *vlW1, *vlB1, *vlW2, *vlB2;
  const unsigned short *wsb;
  float *out;
};

DEV bf16x8 ldAx(const unsigned* buf, int stride, int mbase, int cbase, int lane) {
  return *(const bf16x8*)(buf + (mbase + (lane & 15)) * stride + cbase +
                          ((lane >> 4) << 2));
}
DEV bf16x8 ldBw(const float* q) {
  bf16x8 r;
#pragma unroll
  for (int j = 0; j < 8; ++j) r[j] = (short)f2bf_rn(q[j]);
  return r;
}
template <bool WSB>
DEV bf16x8 ldB(const unsigned short* wb, const float* wf, int off) {
  if constexpr (WSB) return *(const bf16x8*)(wb + off);
  else return ldBw(wf + off);
}

__global__ __launch_bounds__(256) void convw_kernel(const float *qkv,
                                                    const float *o,
                                                    const float *f1,
                                                    const float *f2,
                                                    unsigned short *ws) {
  int i = blockIdx.x * 256 + threadIdx.x;
  if (i < WS_O) ws[i] = f2bf_rn(qkv[i - WS_Q]);
  else if (i < WS_F1) ws[i] = f2bf_rn(o[i - WS_O]);
  else if (i < WS_F2) ws[i] = f2bf_rn(f1[i - WS_F1]);
  else if (i < WS_TOT) ws[i] = f2bf_rn(f2[i - WS_F2]);
}

template <bool WSB>
__global__ __launch_bounds__(768, 1) void battle_kernel(Params p) {
  __shared__ __align__(16) unsigned tokp[192 * ST];
  __shared__ __align__(16) unsigned xln[192 * ST];
  __shared__ __align__(16) unsigned area[192 * ST];
  __shared__ int svalid[MS_], sposc[MS_];

  const int b = blockIdx.x;
  const int tid = threadIdx.x;
  const int lane = tid & 63;
  const int wave = tid >> 6;           // 0..11
  const bool hasrow = tid < S_;
  const float *sc = p.scalars + b * 19;

  float *areaF = (float *)area;
  unsigned short *tok16 = (unsigned short *)tokp;
  unsigned short *xln16 = (unsigned short *)xln;
  unsigned short *P16 = (unsigned short *)area;
  unsigned short *vt16 = (unsigned short *)(area + VT_OFF);

  float *hexcont = (float *)area;
  int   *cids    = (int *)area + 5440;
  float *obsch   = (float *)area + 5632;

  if (tid < D_) {
    float g0 = sc[1] * 0.02f, g1 = sc[4] * 0.1f, g2 = sc[5] * 0.1f;
    float g3 = sc[6], g4 = sc[3];
    const float *w = p.gW + tid * 5;
    areaF[GV_OFF + tid] = p.gB[tid] + g0 * w[0] + g1 * w[1] + g2 * w[2] +
                          g3 * w[3] + g4 * w[4];
  }
  for (int i = tid; i < H_ * HEXC_; i += 768) hexcont[i] = 0.f;
  for (int i = tid; i < H_; i += 768) { cids[i] = 0; obsch[i] = 0.f; }
  if (tid >= 189 && tid < 192) {
    for (int c = 0; c < 64; ++c) tokp[tid * ST + c] = 0u;
  }
  __syncthreads();

  if (tid < MS_) {
    const float *st = p.stacks + (b * MS_ + tid) * 35;
    int pos = (int)st[18];
    float alive = st[23];
    int ns = p.n_stacks[b];
    bool valid = (pos >= 0) && (pos < H_) && (alive >= 0.5f) && (tid < ns);
    svalid[tid] = valid ? 1 : 0;
    sposc[tid] = min(max(pos, 0), H_ - 1);
    if (valid) {
      float maxhp = fmaxf(st[4], 1.0f);
      float *hc = hexcont + pos * HEXC_;
      hc[0] = 1.0f;
      hc[1] = st[2] * 1e-3f;
      hc[2] = st[3] / maxhp;
      hc[3] = st[8] * 0.01f;  hc[4] = st[9] * 0.01f;
      hc[5] = st[10] * 0.01f; hc[6] = st[11] * 0.01f;
      hc[7] = st[12] * 0.01f; hc[8] = st[13] * 0.01f;
      hc[9] = st[14] * 0.01f; hc[10] = st[15] * 0.01f;
      hc[11] = st[16] * 0.05f; hc[12] = st[17] * 0.05f;
      float s20 = st[20];
      hc[13] = s20;
      hc[14] = (s20 == sc[3]) ? 1.f : 0.f;
      hc[15] = alive;
      hc[16] = st[24]; hc[17] = st[25]; hc[18] = st[26];
      hc[19] = st[27]; hc[20] = st[28]; hc[21] = st[29];
      hc[22] = st[30];
      hc[23] = st[31] * (1.f / 30.f);
      hc[24] = st[33] * 0.2f;
      hc[25] = st[34] * 0.1f;
      hc[26] = (st[0] == sc[2]) ? 1.f : 0.f;
      hc[27] = 0.f; hc[28] = 0.f;
      cids[pos] = min((int)st[1], NCT_ - 1);
    }
  }
  if (tid >= 64 && tid < 64 + MOB_) {
    const float *ob = p.obstacles + (b * MOB_ + (tid - 64)) * 3;
    int opos = (int)ob[2];
    if (ob[0] > 0.f && opos >= 0 && opos < H_) obsch[opos] = 1.0f;
  }
  __syncthreads();

  if (tid < H_) {
    const int r = tid;
    float f[HEXC_ + CE_];
#pragma unroll
    for (int c = 0; c < HEXC_; ++c) f[c] = hexcont[r * HEXC_ + c];
    f[27] = p.reach[b * H_ + r];
    f[28] = obsch[r];
    int cid = cids[r];
#pragma unroll
    for (int e = 0; e < CE_; ++e) f[HEXC_ + e] = p.cemb[cid * CE_ + e];
    float sum = 0.f;
    for (int d2 = 0; d2 < 64; ++d2) {
      const float *w0 = p.hexW + (2 * d2) * 45;
      const float *w1 = w0 + 45;
      float a0 = p.hexB[2 * d2], a1 = 0.f, a2 = 0.f, a3 = 0.f;
      float b0 = p.hexB[2 * d2 + 1], b1 = 0.f, b2 = 0.f, b3 = 0.f;
#pragma unroll
      for (int k = 0; k < 44; k += 4) {
        a0 = fmaf(f[k], w0[k], a0);       a1 = fmaf(f[k + 1], w0[k + 1], a1);
        a2 = fmaf(f[k + 2], w0[k + 2], a2); a3 = fmaf(f[k + 3], w0[k + 3], a3);
        b0 = fmaf(f[k], w1[k], b0);       b1 = fmaf(f[k + 1], w1[k + 1], b1);
        b2 = fmaf(f[k + 2], w1[k + 2], b2); b3 = fmaf(f[k + 3], w1[k + 3], b3);
      }
      a0 = fmaf(f[44], w0[44], a0);
      b0 = fmaf(f[44], w1[44], b0);
      float va = (a0 + a1) + (a2 + a3), vb = (b0 + b1) + (b2 + b3);
      tokp[r * ST + d2] = pack2(va, vb);
      sum += va + vb;
    }
    float m = sum * (1.f / 128.f);
    float var = 0.f;
#pragma unroll 4
    for (int d2 = 0; d2 < 64; ++d2) {
      unsigned w = tokp[r * ST + d2];
      float t0 = lo2f(w) - m, t1 = hi2f(w) - m;
      var = fmaf(t0, t0, var); var = fmaf(t1, t1, var);
    }
    float rs = rsqrtf(var * (1.f / 128.f) + 1e-5f);
#pragma unroll 2
    for (int d2 = 0; d2 < 64; ++d2) {
      unsigned w = tokp[r * ST + d2];
      int d = 2 * d2;
      float v0 = (lo2f(w) - m) * rs * p.hexG[d] + p.hexBe[d] +
                 p.pos_emb[r * D_ + d] + p.tte[d] + areaF[GV_OFF + d];
      float v1 = (hi2f(w) - m) * rs * p.hexG[d + 1] + p.hexBe[d + 1] +
                 p.pos_emb[r * D_ + d + 1] + p.tte[d + 1] + areaF[GV_OFF + d + 1];
      tokp[r * ST + d2] = pack2(v0, v1);
    }
  } else if (tid < S_) {
    const int which = tid - H_;
    float f0, f1, f2, f3, f4;
    if (which == 0) {
      f0 = sc[8];  f1 = sc[11] * (1.f / 300.f);
      f2 = sc[10] * 0.1f; f3 = sc[12] * 0.1f; f4 = 0.f;
    } else {
      f0 = sc[14]; f1 = sc[17] * (1.f / 300.f);
      f2 = sc[16] * 0.1f; f3 = sc[18] * 0.1f; f4 = 1.f;
    }
    const int r = tid;
    float sum = 0.f;
    for (int d2 = 0; d2 < 64; ++d2) {
      const float *w0 = p.heroW + (2 * d2) * 5;
      const float *w1 = w0 + 5;
      float va = p.heroB[2 * d2] + f0 * w0[0] + f1 * w0[1] + f2 * w0[2] + f3 * w0[3] + f4 * w0[4];
      float vb = p.heroB[2 * d2 + 1] + f0 * w1[0] + f1 * w1[1] + f2 * w1[2] + f3 * w1[3] + f4 * w1[4];
      tokp[r * ST + d2] = pack2(va, vb);
      sum += va + vb;
    }
    float m = sum * (1.f / 128.f);
    float var = 0.f;
    for (int d2 = 0; d2 < 64; ++d2) {
      unsigned w = tokp[r * ST + d2];
      float t0 = lo2f(w) - m, t1 = hi2f(w) - m;
      var = fmaf(t0, t0, var); var = fmaf(t1, t1, var);
    }
    float rs = rsqrtf(var * (1.f / 128.f) + 1e-5f);
    for (int d2 = 0; d2 < 64; ++d2) {
      unsigned w = tokp[r * ST + d2];
      int d = 2 * d2;
      float v0 = (lo2f(w) - m) * rs * p.heroG[d] + p.heroBe[d] +
                 p.tte[(1 + which) * D_ + d] + areaF[GV_OFF + d];
      float v1 = (hi2f(w) - m) * rs * p.heroG[d + 1] + p.heroBe[d + 1] +
                 p.tte[(1 + which) * D_ + d + 1] + areaF[GV_OFF + d + 1];
      tokp[r * ST + d2] = pack2(v0, v1);
    }
  }

  const int lrow = tid >> 2;     // LN row (0..191)
  const int lsub = tid & 3;      // LN sub-slice (16 u32 each)

  for (int l = 0; l < NL_; ++l) {
    const float *ln1g = p.ln1g + l * D_, *ln1b = p.ln1b + l * D_;
    const float *qkvW = p.qkvW + l * 3 * D_ * D_, *qkvB = p.qkvB + l * 3 * D_;
    const float *oW = p.oW + l * D_ * D_, *oB = p.oB + l * D_;
    const float *ln2g = p.ln2g + l * D_, *ln2b = p.ln2b + l * D_;
    const float *f1W = p.f1W + l * 4 * D_ * D_, *f1B = p.f1B + l * 4 * D_;
    const float *f2W = p.f2W + l * 4 * D_ * D_, *f2B = p.f2B + l * D_;
    const unsigned short *qkvWb = p.wsb + WS_Q + l * 384 * 128;
    const unsigned short *oWb = p.wsb + WS_O + l * 128 * 128;
    const unsigned short *f1Wb = p.wsb + WS_F1 + l * 512 * 128;
    const unsigned short *f2Wb = p.wsb + WS_F2 + l * 128 * 512;

    __syncthreads();

    // LN1 -> xln (4 lanes per row)
    if (lrow < S_) {
      float s = 0.f;
#pragma unroll
      for (int i = 0; i < 16; ++i) {
        unsigned w = tokp[lrow * ST + lsub * 16 + i];
        s += lo2f(w) + hi2f(w);
      }
      s += __shfl_xor(s, 1); s += __shfl_xor(s, 2);
      float m = s * (1.f / 128.f);
      float v = 0.f;
#pragma unroll
      for (int i = 0; i < 16; ++i) {
        unsigned w = tokp[lrow * ST + lsub * 16 + i];
        float t0 = lo2f(w) - m, t1 = hi2f(w) - m;
        v = fmaf(t0, t0, v); v = fmaf(t1, t1, v);
      }
      v += __shfl_xor(v, 1); v += __shfl_xor(v, 2);
      float rs = rsqrtf(v * (1.f / 128.f) + 1e-5f);
#pragma unroll
      for (int i = 0; i < 16; ++i) {
        int d2 = lsub * 16 + i, d = 2 * d2;
        unsigned w = tokp[lrow * ST + d2];
        xln[lrow * ST + d2] = pack2((lo2f(w) - m) * rs * ln1g[d] + ln1b[d],
                                    (hi2f(w) - m) * rs * ln1g[d + 1] + ln1b[d + 1]);
      }
    } else {
#pragma unroll
      for (int i = 0; i < 16; ++i) xln[lrow * ST + lsub * 16 + i] = 0u;
    }
    __syncthreads();

    f32x4 oacc[4][2];

#pragma unroll
    for (int h = 0; h < NH_; ++h) {
#pragma unroll
      for (int nd = 0; nd < 2; ++nd) oacc[h][nd] = {0.f, 0.f, 0.f, 0.f};

      // Phase A: QKV projection, 12 jobs = 12 waves (nt of 6 x mhalf)
      {
        int ntg = wave >> 1, mh = wave & 1;
        int nrow0, c16 = 0, isV = 0, ntd = 0;
        if (ntg < 2)      { nrow0 = h * 32 + ntg * 16;            c16 = ntg * 16; }
        else if (ntg < 4) { nrow0 = 128 + h * 32 + (ntg - 2) * 16; c16 = 32 + (ntg - 2) * 16; }
        else              { nrow0 = 256 + h * 32 + (ntg - 4) * 16; isV = 1; ntd = ntg - 4; }
        int roff = (nrow0 + (lane & 15)) * 128;
        int koff = (lane >> 4) << 3;
        bf16x8 b0 = ldB<WSB>(qkvWb, qkvW, roff + koff);
        bf16x8 b1 = ldB<WSB>(qkvWb, qkvW, roff + 32 + koff);
        bf16x8 b2 = ldB<WSB>(qkvWb, qkvW, roff + 64 + koff);
        bf16x8 b3 = ldB<WSB>(qkvWb, qkvW, roff + 96 + koff);
        float bv = qkvB[nrow0 + (lane & 15)];
        int col16 = c16 + (lane & 15);
#pragma unroll 1
        for (int mt = mh * 6; mt < mh * 6 + 6; ++mt) {
          f32x4 acc = {bv, bv, bv, bv};
          acc = MFMA16(ldAx(xln, ST, mt * 16, 0, lane), b0, acc, 0, 0, 0);
          acc = MFMA16(ldAx(xln, ST, mt * 16, 16, lane), b1, acc, 0, 0, 0);
          acc = MFMA16(ldAx(xln, ST, mt * 16, 32, lane), b2, acc, 0, 0, 0);
          acc = MFMA16(ldAx(xln, ST, mt * 16, 48, lane), b3, acc, 0, 0, 0);
          int rb = mt * 16 + ((lane >> 4) << 2);
          if (!isV) {
#pragma unroll
            for (int g = 0; g < 4; ++g)
              P16[(rb + g) * (PST * 2) + col16] = f2bf_rn(acc[g]);
          } else {
#pragma unroll
            for (int g = 0; g < 4; ++g)
              vt16[(ntd * 16 + (lane & 15)) * (VTS * 2) + rb + g] = f2bf_rn(acc[g]);
          }
        }
      }
      __syncthreads();

      // Phase B: Q for own m-tile + all K fragments
      bf16x8 qf = ldAx(area, PST, wave * 16, 0, lane);
      bf16x8 kf[12];
#pragma unroll
      for (int nt = 0; nt < 12; ++nt)
        kf[nt] = ldAx(area, PST, nt * 16, 16, lane);
      float mrun = -1e30f, lrun = 0.f;
      const int srow = wave * 16 + (lane & 15);
      const int ssub = lane >> 4;  // 0..3, u32 cols ssub*8..+8
      __syncthreads();

#pragma unroll
      for (int t = 0; t < 3; ++t) {
        // QK^T for own 16 rows x 64 cols
        {
          int rb = wave * 16 + ((lane >> 4) << 2);
#pragma unroll
          for (int ntl = 0; ntl < 4; ++ntl) {
            f32x4 s = {0.f, 0.f, 0.f, 0.f};
            s = MFMA16(qf, kf[t * 4 + ntl], s, 0, 0, 0);
            int col16 = ntl * 16 + (lane & 15);
#pragma unroll
            for (int g = 0; g < 4; ++g)
              P16[(rb + g) * (PST * 2) + col16] = f2bf_rn(s[g]);
          }
        }
        // in-wave softmax: 4 lanes per row
        {
          float tm = -1e30f;
          int cb = ssub * 8;
#pragma unroll
          for (int i = 0; i < 8; ++i) {
            int c2 = cb + i;
            unsigned w = area[srow * PST + c2];
            float v0 = lo2f(w) * SCALE, v1 = hi2f(w) * SCALE;
            if (t == 2 && c2 == 30) v1 = -1e30f;
            if (t == 2 && c2 == 31) { v0 = -1e30f; v1 = -1e30f; }
            tm = fmaxf(tm, fmaxf(v0, v1));
          }
          tm = fmaxf(tm, __shfl_xor(tm, 16));
          tm = fmaxf(tm, __shfl_xor(tm, 32));
          float mnew = fmaxf(mrun, tm);
          float corrv = __expf(mrun - mnew);
          float ts = 0.f;
#pragma unroll
          for (int i = 0; i < 8; ++i) {
            int c2 = cb + i;
            unsigned w = area[srow * PST + c2];
            float e0 = __expf(lo2f(w) * SCALE - mnew);
            float e1 = __expf(hi2f(w) * SCALE - mnew);
            if (t == 2 && c2 == 30) e1 = 0.f;
            if (t == 2 && c2 == 31) { e0 = 0.f; e1 = 0.f; }
            ts += e0 + e1;
            area[srow * PST + c2] = pack2(e0, e1);
          }
          ts += __shfl_xor(ts, 16);
          ts += __shfl_xor(ts, 32);
          lrun = lrun * corrv + ts;
          mrun = mnew;
          if (ssub == 0) {
            areaF[CORR_OFF + srow] = corrv;
            if (t == 2) areaF[LSUM_OFF + srow] = lrun;
          }
        }
        // PV for own rows
        {
          int rb = wave * 16 + ((lane >> 4) << 2);
          float c0 = areaF[CORR_OFF + rb], c1 = areaF[CORR_OFF + rb + 1];
          float c2v = areaF[CORR_OFF + rb + 2], c3 = areaF[CORR_OFF + rb + 3];
#pragma unroll
          for (int nd = 0; nd < 2; ++nd) {
            f32x4 a = oacc[h][nd];
            a[0] *= c0; a[1] *= c1; a[2] *= c2v; a[3] *= c3;
#pragma unroll
            for (int kt = 0; kt < 2; ++kt) {
              bf16x8 af = ldAx(area, PST, wave * 16, kt * 16, lane);
              bf16x8 bv = *(const bf16x8*)(area + VT_OFF +
                            (nd * 16 + (lane & 15)) * VTS + t * 32 + kt * 16 +
                            ((lane >> 4) << 2));
              a = MFMA16(af, bv, a, 0, 0, 0);
            }
            oacc[h][nd] = a;
          }
          if (t == 2) {
            float i0 = 1.f / areaF[LSUM_OFF + rb];
            float i1 = 1.f / areaF[LSUM_OFF + rb + 1];
            float i2 = 1.f / areaF[LSUM_OFF + rb + 2];
            float i3 = 1.f / areaF[LSUM_OFF + rb + 3];
#pragma unroll
            for (int nd = 0; nd < 2; ++nd) {
              f32x4 a = oacc[h][nd];
              a[0] *= i0; a[1] *= i1; a[2] *= i2; a[3] *= i3;
              oacc[h][nd] = a;
            }
          }
        }
      }
      __syncthreads();
    }  // heads

    // O write -> xln (own m-tile, all heads)
#pragma unroll
    for (int h = 0; h < NH_; ++h) {
      int rb = wave * 16 + ((lane >> 4) << 2);
#pragma unroll
      for (int nd = 0; nd < 2; ++nd) {
        int col16 = h * 32 + nd * 16 + (lane & 15);
        f32x4 a = oacc[h][nd];
#pragma unroll
        for (int g = 0; g < 4; ++g)
          xln16[(rb + g) * (ST * 2) + col16] = f2bf_rn(a[g]);
      }
    }
    __syncthreads();

    // O-projection + residual RMW (16 jobs stride 12)
#pragma unroll 1
    for (int job = wave; job < 16; job += 12) {
      int nt = job >> 1, mh = job & 1;
      int roff = (nt * 16 + (lane & 15)) * 128;
      int koff = (lane >> 4) << 3;
      bf16x8 b0 = ldB<WSB>(oWb, oW, roff + koff);
      bf16x8 b1 = ldB<WSB>(oWb, oW, roff + 32 + koff);
      bf16x8 b2 = ldB<WSB>(oWb, oW, roff + 64 + koff);
      bf16x8 b3 = ldB<WSB>(oWb, oW, roff + 96 + koff);
      float bv = oB[nt * 16 + (lane & 15)];
      int col16 = nt * 16 + (lane & 15);
#pragma unroll 1
      for (int mt = mh * 6; mt < mh * 6 + 6; ++mt) {
        f32x4 acc = {bv, bv, bv, bv};
        acc = MFMA16(ldAx(xln, ST, mt * 16, 0, lane), b0, acc, 0, 0, 0);
        acc = MFMA16(ldAx(xln, ST, mt * 16, 16, lane), b1, acc, 0, 0, 0);
        acc = MFMA16(ldAx(xln, ST, mt * 16, 32, lane), b2, acc, 0, 0, 0);
        acc = MFMA16(ldAx(xln, ST, mt * 16, 48, lane), b3, acc, 0, 0, 0);
        int rb = mt * 16 + ((lane >> 4) << 2);
#pragma unroll
        for (int g = 0; g < 4; ++g) {
          int a16 = (rb + g) * (ST * 2) + col16;
          float old = __uint_as_float((unsigned)tok16[a16] << 16);
          tok16[a16] = f2bf_rn(old + acc[g]);
        }
      }
    }
    __syncthreads();

    // LN2 -> xln (4 lanes per row)
    if (lrow < S_) {
      float s = 0.f;
#pragma unroll
      for (int i = 0; i < 16; ++i) {
        unsigned w = tokp[lrow * ST + lsub * 16 + i];
        s += lo2f(w) + hi2f(w);
      }
      s += __shfl_xor(s, 1); s += __shfl_xor(s, 2);
      float m = s * (1.f / 128.f);
      float v = 0.f;
#pragma unroll
      for (int i = 0; i < 16; ++i) {
        unsigned w = tokp[lrow * ST + lsub * 16 + i];
        float t0 = lo2f(w) - m, t1 = hi2f(w) - m;
        v = fmaf(t0, t0, v); v = fmaf(t1, t1, v);
      }
      v += __shfl_xor(v, 1); v += __shfl_xor(v, 2);
      float rs = rsqrtf(v * (1.f / 128.f) + 1e-5f);
#pragma unroll
      for (int i = 0; i < 16; ++i) {
        int d2 = lsub * 16 + i, d = 2 * d2;
        unsigned w = tokp[lrow * ST + d2];
        xln[lrow * ST + d2] = pack2((lo2f(w) - m) * rs * ln2g[d] + ln2b[d],
                                    (hi2f(w) - m) * rs * ln2g[d + 1] + ln2b[d + 1]);
      }
    } else {
#pragma unroll
      for (int i = 0; i < 16; ++i) xln[lrow * ST + lsub * 16 + i] = 0u;
    }
    __syncthreads();

    // FFN: jobs {wave, wave+12}; 6-mt accumulators
    const int ja = wave;
    const bool hasb = wave < 4;
    const int jb = wave + 12;
    const int nta = ja >> 1, mha = ja & 1;
    const int ntb = jb >> 1, mhb = jb & 1;
    f32x4 acca[6], accb[6];
    {
      float bva = f2B[nta * 16 + (lane & 15)];
#pragma unroll
      for (int i = 0; i < 6; ++i) acca[i] = {bva, bva, bva, bva};
      float bvb = hasb ? f2B[ntb * 16 + (lane & 15)] : 0.f;
#pragma unroll
      for (int i = 0; i < 6; ++i) accb[i] = {bvb, bvb, bvb, bvb};
    }
    for (int chunk = 0; chunk < 4; ++chunk) {
      // FFN1 (16 jobs stride 12) -> relu bf16 into area
#pragma unroll 1
      for (int job = wave; job < 16; job += 12) {
        int nt = job >> 1, mh = job & 1;
        int roff = (chunk * 128 + nt * 16 + (lane & 15)) * 128;
        int koff = (lane >> 4) << 3;
        bf16x8 b0 = ldB<WSB>(f1Wb, f1W, roff + koff);
        bf16x8 b1 = ldB<WSB>(f1Wb, f1W, roff + 32 + koff);
        bf16x8 b2 = ldB<WSB>(f1Wb, f1W, roff + 64 + koff);
        bf16x8 b3 = ldB<WSB>(f1Wb, f1W, roff + 96 + koff);
        float bv = f1B[chunk * 128 + nt * 16 + (lane & 15)];
        int col16 = nt * 16 + (lane & 15);
#pragma unroll 1
        for (int mt = mh * 6; mt < mh * 6 + 6; ++mt) {
          f32x4 acc = {bv, bv, bv, bv};
          acc = MFMA16(ldAx(xln, ST, mt * 16, 0, lane), b0, acc, 0, 0, 0);
          acc = MFMA16(ldAx(xln, ST, mt * 16, 16, lane), b1, acc, 0, 0, 0);
          acc = MFMA16(ldAx(xln, ST, mt * 16, 32, lane), b2, acc, 0, 0, 0);
          acc = MFMA16(ldAx(xln, ST, mt * 16, 48, lane), b3, acc, 0, 0, 0);
          int rb = mt * 16 + ((lane >> 4) << 2);
#pragma unroll
          for (int g = 0; g < 4; ++g)
            P16[(rb + g) * (ST * 2) + col16] = f2bf_rn(fmaxf(acc[g], 0.f));
        }
      }
      __syncthreads();
      // FFN2 partials: job a (all waves), job b (waves 0-3)
      {
        int roff = (nta * 16 + (lane & 15)) * 512 + chunk * 128;
        int koff = (lane >> 4) << 3;
        bf16x8 b0 = ldB<WSB>(f2Wb, f2W, roff + koff);
        bf16x8 b1 = ldB<WSB>(f2Wb, f2W, roff + 32 + koff);
        bf16x8 b2 = ldB<WSB>(f2Wb, f2W, roff + 64 + koff);
        bf16x8 b3 = ldB<WSB>(f2Wb, f2W, roff + 96 + koff);
#pragma unroll
        for (int i = 0; i < 6; ++i) {
          int mt = mha * 6 + i;
          f32x4 a = acca[i];
          a = MFMA16(ldAx(area, ST, mt * 16, 0, lane), b0, a, 0, 0, 0);
          a = MFMA16(ldAx(area, ST, mt * 16, 16, lane), b1, a, 0, 0, 0);
          a = MFMA16(ldAx(area, ST, mt * 16, 32, lane), b2, a, 0, 0, 0);
          a = MFMA16(ldAx(area, ST, mt * 16, 48, lane), b3, a, 0, 0, 0);
          acca[i] = a;
        }
      }
      if (hasb) {
        int roff = (ntb * 16 + (lane & 15)) * 512 + chunk * 128;
        int koff = (lane >> 4) << 3;
        bf16x8 b0 = ldB<WSB>(f2Wb, f2W, roff + koff);
        bf16x8 b1 = ldB<WSB>(f2Wb, f2W, roff + 32 + koff);
        bf16x8 b2 = ldB<WSB>(f2Wb, f2W, roff + 64 + koff);
        bf16x8 b3 = ldB<WSB>(f2Wb, f2W, roff + 96 + koff);
#pragma unroll
        for (int i = 0; i < 6; ++i) {
          int mt = mhb * 6 + i;
          f32x4 a = accb[i];
          a = MFMA16(ldAx(area, ST, mt * 16, 0, lane), b0, a, 0, 0, 0);
          a = MFMA16(ldAx(area, ST, mt * 16, 16, lane), b1, a, 0, 0, 0);
          a = MFMA16(ldAx(area, ST, mt * 16, 32, lane), b2, a, 0, 0, 0);
          a = MFMA16(ldAx(area, ST, mt * 16, 48, lane), b3, a, 0, 0, 0);
          accb[i] = a;
        }
      }
      __syncthreads();
    }
    // FFN2 residual RMW
    {
      int col16 = nta * 16 + (lane & 15);
#pragma unroll
      for (int i = 0; i < 6; ++i) {
        int rb = (mha * 6 + i) * 16 + ((lane >> 4) << 2);
        f32x4 a = acca[i];
#pragma unroll
        for (int g = 0; g < 4; ++g) {
          int a16 = (rb + g) * (ST * 2) + col16;
          float old = __uint_as_float((unsigned)tok16[a16] << 16);
          tok16[a16] = f2bf_rn(old + a[g]);
        }
      }
    }
    if (hasb) {
      int col16 = ntb * 16 + (lane & 15);
#pragma unroll
      for (int i = 0; i < 6; ++i) {
        int rb = (mhb * 6 + i) * 16 + ((lane >> 4) << 2);
        f32x4 a = accb[i];
#pragma unroll
        for (int g = 0; g < 4; ++g) {
          int a16 = (rb + g) * (ST * 2) + col16;
          float old = __uint_as_float((unsigned)tok16[a16] << 16);
          tok16[a16] = f2bf_rn(old + a[g]);
        }
      }
    }
  }  // layers
  __syncthreads();

  // post-LN (4 lanes per row, in place)
  if (lrow < S_) {
    float s = 0.f;
#pragma unroll
    for (int i = 0; i < 16; ++i) {
      unsigned w = tokp[lrow * ST + lsub * 16 + i];
      s += lo2f(w) + hi2f(w);
    }
    s += __shfl_xor(s, 1); s += __shfl_xor(s, 2);
    float m = s * (1.f / 128.f);
    float v = 0.f;
#pragma unroll
    for (int i = 0; i < 16; ++i) {
      unsigned w = tokp[lrow * ST + lsub * 16 + i];
      float t0 = lo2f(w) - m, t1 = hi2f(w) - m;
      v = fmaf(t0, t0, v); v = fmaf(t1, t1, v);
    }
    v += __shfl_xor(v, 1); v += __shfl_xor(v, 2);
    float rs = rsqrtf(v * (1.f / 128.f) + 1e-5f);
#pragma unroll
    for (int i = 0; i < 16; ++i) {
      int d2 = lsub * 16 + i, d = 2 * d2;
      unsigned w = tokp[lrow * ST + d2];
      tokp[lrow * ST + d2] = pack2((lo2f(w) - m) * rs * p.plng[d] + p.plnb[d],
                                   (hi2f(w) - m) * rs * p.plng[d + 1] + p.plnb[d + 1]);
    }
  }
  __syncthreads();

  if (tid < D_) {
    const int d2 = tid >> 1;
    const bool hi = tid & 1;
    float s0 = 0.f, s1 = 0.f;
    int r = 0;
    for (; r + 2 <= S_; r += 2) {
      unsigned w0 = tokp[r * ST + d2], w1 = tokp[(r + 1) * ST + d2];
      s0 += hi ? hi2f(w0) : lo2f(w0);
      s1 += hi ? hi2f(w1) : lo2f(w1);
    }
    unsigned wl = tokp[(S_ - 1) * ST + d2];
    s0 += hi ? hi2f(wl) : lo2f(wl);
    areaF[PO_OFF + tid] = (s0 + s1) * (1.f / (float)S_);
  }
  __syncthreads();
  if (tid < D_) {
    const float *wa = p.atW1 + tid * D_;
    const float *wv = p.vlW1 + tid * D_;
    float a0 = p.atB1[tid], a1 = 0.f, vv0 = p.vlB1[tid], vv1 = 0.f;
#pragma unroll 4
    for (int k = 0; k < D_; k += 2) {
      float pk0 = areaF[PO_OFF + k], pk1 = areaF[PO_OFF + k + 1];
      a0 = fmaf(pk0, wa[k], a0);   a1 = fmaf(pk1, wa[k + 1], a1);
      vv0 = fmaf(pk0, wv[k], vv0); vv1 = fmaf(pk1, wv[k + 1], vv1);
    }
    areaF[H1_OFF + tid] = fmaxf(a0 + a1, 0.f);
    areaF[H2_OFF + tid] = fmaxf(vv0 + vv1, 0.f);
  }
  __syncthreads();

  if (tid < H_) {
    float hh[64];
#pragma unroll
    for (int j = 0; j < 64; ++j) hh[j] = p.hxB1[j];
    for (int kb = 0; kb < 8; ++kb) {
      float xr[16];
#pragma unroll
      for (int i2 = 0; i2 < 8; ++i2) {
        unsigned w = tokp[tid * ST + kb * 8 + i2];
        xr[2 * i2] = lo2f(w); xr[2 * i2 + 1] = hi2f(w);
      }
      const float *w = p.hxW1 + kb * 16;
#pragma unroll
      for (int j = 0; j < 64; ++j) {
#pragma unroll
        for (int i = 0; i < 16; ++i)
          hh[j] = fmaf(xr[i], w[j * D_ + i], hh[j]);
      }
    }
    float o = p.hxB2[0];
#pragma unroll
    for (int j = 0; j < 64; ++j) o = fmaf(fmaxf(hh[j], 0.f), p.hxW2[j], o);
    p.out[OFF_HEX + b * H_ + tid] = o;
  }
  if (tid < NAT_) {
    const float *w = p.atW2 + tid * D_;
    float o0 = p.atB2[tid], o1 = 0.f, o2 = 0.f, o3 = 0.f;
#pragma unroll 4
    for (int k = 0; k < D_; k += 4) {
      o0 = fmaf(areaF[H1_OFF + k], w[k], o0);
      o1 = fmaf(areaF[H1_OFF + k + 1], w[k + 1], o1);
      o2 = fmaf(areaF[H1_OFF + k + 2], w[k + 2], o2);
      o3 = fmaf(areaF[H1_OFF + k + 3], w[k + 3], o3);
    }
    p.out[b * NAT_ + tid] = (o0 + o1) + (o2 + o3);
  }
  if (tid == 190) {
    float o0 = p.vlB2[0], o1 = 0.f, o2 = 0.f, o3 = 0.f;
#pragma unroll 4
    for (int k = 0; k < D_; k += 4) {
      o0 = fmaf(areaF[H2_OFF + k], p.vlW2[k], o0);
      o1 = fmaf(areaF[H2_OFF + k + 1], p.vlW2[k + 1], o1);
      o2 = fmaf(areaF[H2_OFF + k + 2], p.vlW2[k + 2], o2);
      o3 = fmaf(areaF[H2_OFF + k + 3], p.vlW2[k + 3], o3);
    }
    p.out[OFF_VAL + b] = (o0 + o1) + (o2 + o3);
  }
  if (tid >= 32 && tid < 32 + MS_) {
    int si = tid - 32;
    float o;
    if (svalid[si]) {
      int r = sposc[si];
      float hh[64];
#pragma unroll
      for (int j = 0; j < 64; ++j) hh[j] = p.tgB1[j];
      for (int kb = 0; kb < 8; ++kb) {
        float xr[16];
#pragma unroll
        for (int i2 = 0; i2 < 8; ++i2) {
          unsigned w = tokp[r * ST + kb * 8 + i2];
          xr[2 * i2] = lo2f(w); xr[2 * i2 + 1] = hi2f(w);
        }
        const float *w = p.tgW1 + kb * 16;
#pragma unroll
        for (int j = 0; j < 64; ++j) {
#pragma unroll
          for (int i = 0; i < 16; ++i)
            hh[j] = fmaf(xr[i], w[j * D_ + i], hh[j]);
        }
      }
      o = p.tgB2[0];
#pragma unroll
      for (int j = 0; j < 64; ++j) o = fmaf(fmaxf(hh[j], 0.f), p.tgW2[j], o);
    } else {
      o = -1e9f;
    }
    p.out[OFF_TGT + b * MS_ + si] = o;
  }
}

extern "C" void kernel_launch(void* const* d_in, const int* in_sizes, int n_in,
                              void* d_out, int out_size, void* d_ws, size_t ws_size,
                              hipStream_t stream) {
  (void)in_sizes; (void)n_in; (void)out_size;
  Params p;
  p.scalars = (const float *)d_in[0];
  p.stacks = (const float *)d_in[1];
  p.obstacles = (const float *)d_in[2];
  p.reach = (const float *)d_in[3];
  p.n_stacks = (const int *)d_in[4];
  p.cemb = (const float *)d_in[5];
  p.pos_emb = (const float *)d_in[6];
  p.tte = (const float *)d_in[7];
  p.hexW = (const float *)d_in[8];  p.hexB = (const float *)d_in[9];
  p.hexG = (const float *)d_in[10]; p.hexBe = (const float *)d_in[11];
  p.heroW = (const float *)d_in[12]; p.heroB = (const float *)d_in[13];
  p.heroG = (const float *)d_in[14]; p.heroBe = (const float *)d_in[15];
  p.gW = (const float *)d_in[16]; p.gB = (const float *)d_in[17];
  p.ln1g = (const float *)d_in[18]; p.ln1b = (const float *)d_in[19];
  p.qkvW = (const float *)d_in[20]; p.qkvB = (const float *)d_in[21];
  p.oW = (const float *)d_in[22]; p.oB = (const float *)d_in[23];
  p.ln2g = (const float *)d_in[24]; p.ln2b = (const float *)d_in[25];
  p.f1W = (const float *)d_in[26]; p.f1B = (const float *)d_in[27];
  p.f2W = (const float *)d_in[28]; p.f2B = (const float *)d_in[29];
  p.plng = (const float *)d_in[30]; p.plnb = (const float *)d_in[31];
  p.atW1 = (const float *)d_in[32]; p.atB1 = (const float *)d_in[33];
  p.atW2 = (const float *)d_in[34]; p.atB2 = (const float *)d_in[35];
  p.hxW1 = (const float *)d_in[36]; p.hxB1 = (const float *)d_in[37];
  p.hxW2 = (const float *)d_in[38]; p.hxB2 = (const float *)d_in[39];
  p.tgW1 = (const float *)d_in[40]; p.tgB1 = (const float *)d_in[41];
  p.tgW2 = (const float *)d_in[42]; p.tgB2 = (const float *)d_in[43];
  p.vlW1 = (const float *)d_in[44]; p.vlB1 = (const float *)d_in[45];
  p.vlW2 = (const float *)d_in[46]; p.vlB2 = (const float *)d_in[47];
  p.out = (float *)d_out;
  bool usews = ws_size >= (size_t)WS_TOT * 2;
  if (usews) {
    p.wsb = (const unsigned short *)d_ws;
    convw_kernel<<<dim3((WS_TOT + 255) / 256), dim3(256), 0, stream>>>(
        p.qkvW, p.oW, p.f1W, p.f2W, (unsigned short *)d_ws);
    battle_kernel<true><<<dim3(B_), dim3(768), 0, stream>>>(p);
  } else {
    p.wsb = nullptr;
    battle_kernel<false><<<dim3(B_), dim3(768), 0, stream>>>(p);
  }
}